// Round 1
// baseline (205.158 us; speedup 1.0000x reference)
//
#include <hip/hip_runtime.h>
#include <hip/hip_bf16.h>

#define T_TOK 4096
#define H_DIM 1024
#define I_DIM 512
#define E_EXP 16
#define BM    128
#define BK    32

using bf16x8   = __attribute__((ext_vector_type(8))) short;
using floatx4  = __attribute__((ext_vector_type(4))) float;
using ushort4v = __attribute__((ext_vector_type(4))) unsigned short;

__device__ __forceinline__ unsigned short f2bf(float f) {
  union { float f; unsigned u; } v; v.f = f;
  return (unsigned short)((v.u + 0x7FFFu + ((v.u >> 16) & 1u)) >> 16);  // RNE
}

__device__ __forceinline__ void gld16(const void* g, void* l) {
  __builtin_amdgcn_global_load_lds((const __attribute__((address_space(1))) void*)g,
                                   (__attribute__((address_space(3))) void*)l,
                                   16, 0, 0);
}

// ---------------- schedule: prefix offsets + tile list ----------------
// sched[0..15]  = expert row offsets, sched[16] = total (=T)
// sched[17]     = n_tiles
// sched[18+2t]  = expert id, sched[19+2t] = row0 within expert
__global__ void k_sched(const int* __restrict__ counts, int* __restrict__ sched) {
  if (threadIdx.x == 0 && blockIdx.x == 0) {
    int off = 0, nt = 0;
    for (int e = 0; e < E_EXP; ++e) {
      sched[e] = off;
      int c = counts[e];
      for (int r = 0; r < c; r += BM) {
        sched[18 + 2 * nt] = e;
        sched[19 + 2 * nt] = r;
        ++nt;
      }
      off += c;
    }
    sched[E_EXP] = off;
    sched[17] = nt;
  }
}

// ---------------- fp32 -> bf16 elementwise (x) ----------------
__global__ void k_cvt(const float* __restrict__ src, unsigned short* __restrict__ dst, int n4) {
  int i = blockIdx.x * blockDim.x + threadIdx.x;
  if (i >= n4) return;
  float4 v = ((const float4*)src)[i];
  ushort4v o;
  o.x = f2bf(v.x); o.y = f2bf(v.y); o.z = f2bf(v.z); o.w = f2bf(v.w);
  ((ushort4v*)dst)[i] = o;
}

// ---------------- fp32 [z][R][C] -> bf16 [z][C][R] transpose-convert ----------------
__global__ void k_tcvt(const float* __restrict__ src, unsigned short* __restrict__ dst,
                       int R, int C) {
  __shared__ unsigned short tile[64][65];
  const size_t mat = (size_t)blockIdx.z * (size_t)R * (size_t)C;
  const int c0 = blockIdx.x * 64, r0 = blockIdx.y * 64;
  const int tx = threadIdx.x, ty = threadIdx.y;  // (64, 4)
  #pragma unroll
  for (int rr = ty; rr < 64; rr += 4)
    tile[rr][tx] = f2bf(src[mat + (size_t)(r0 + rr) * C + c0 + tx]);
  __syncthreads();
  #pragma unroll
  for (int cc = ty; cc < 64; cc += 4)
    dst[mat + (size_t)(c0 + cc) * R + r0 + tx] = tile[tx][cc];
}

// ---------------- GEMM A: gu = x_e @ Wgu_e, h = silu(g)*u (bf16 out) ----------------
// xb   : bf16 [T][H]           (K-contiguous)
// wguT : bf16 [E][2I][H]       (K-contiguous rows; rows 0..I-1 = g cols, I..2I-1 = u cols)
// hb   : bf16 [T][I]
__launch_bounds__(256, 2)
__global__ void k_gemm_a(const unsigned short* __restrict__ xb,
                         const unsigned short* __restrict__ wguT,
                         unsigned short* __restrict__ hb,
                         const int* __restrict__ sched) {
  __shared__ unsigned short As[BM * BK];   // [row][k]
  __shared__ unsigned short Bs[BM * BK];   // rows 0..63 g-cols, 64..127 u-cols

  const int nt = sched[17];
  if ((int)blockIdx.y >= nt) return;
  const int e    = sched[18 + 2 * blockIdx.y];
  const int row0 = sched[19 + 2 * blockIdx.y];
  const int base = sched[e];
  const int cnt  = sched[e + 1] - base;
  const int rows = (cnt - row0 < BM) ? (cnt - row0) : BM;
  const int c0   = blockIdx.x * 64;        // g-column base within I

  const int tid = threadIdx.x;
  const int w = tid >> 6, l = tid & 63;
  const int lr = l & 15, q = l >> 4;
  const int srow = l >> 2;          // staging: 4 lanes per 64B row
  const int skc  = (l & 3) * 8;     // staging: 8-elem k sub-chunk

  floatx4 acc[2][8];
  #pragma unroll
  for (int i = 0; i < 2; ++i)
    #pragma unroll
    for (int j = 0; j < 8; ++j) acc[i][j] = (floatx4){0.f, 0.f, 0.f, 0.f};

  const unsigned short* wg = wguT + (size_t)e * (2 * I_DIM) * H_DIM;

  for (int kk = 0; kk < H_DIM; kk += BK) {
    #pragma unroll
    for (int c = 0; c < 2; ++c) {
      const int r = w * 32 + c * 16;             // wave-uniform chunk row base
      // A chunk
      int arow = r + srow;
      int gr = arow < rows ? arow : rows - 1;
      gld16(&xb[(size_t)(base + row0 + gr) * H_DIM + kk + skc], &As[r * BK]);
      // B chunk (g rows then u rows)
      int brow = r + srow;
      int wrow = (brow < 64) ? (c0 + brow) : (I_DIM + c0 + (brow - 64));
      gld16(&wg[(size_t)wrow * H_DIM + kk + skc], &Bs[r * BK]);
    }
    __syncthreads();   // drains vmcnt: staging visible

    bf16x8 af[2];
    #pragma unroll
    for (int i = 0; i < 2; ++i)
      af[i] = *(const bf16x8*)&As[(w * 32 + i * 16 + lr) * BK + q * 8];
    #pragma unroll
    for (int j = 0; j < 8; ++j) {
      bf16x8 bfj = *(const bf16x8*)&Bs[(j * 16 + lr) * BK + q * 8];
      acc[0][j] = __builtin_amdgcn_mfma_f32_16x16x32_bf16(af[0], bfj, acc[0][j], 0, 0, 0);
      acc[1][j] = __builtin_amdgcn_mfma_f32_16x16x32_bf16(af[1], bfj, acc[1][j], 0, 0, 0);
    }
    __syncthreads();   // LDS reads done before next stage overwrites
  }

  // epilogue: h[r][c] = silu(g)*u ; C/D layout: col=lane&15, row=quad*4+reg
  #pragma unroll
  for (int i = 0; i < 2; ++i) {
    const int rl = w * 32 + i * 16 + q * 4;
    #pragma unroll
    for (int r = 0; r < 4; ++r) {
      const int row_local = rl + r;
      if (row_local >= rows) continue;
      const size_t orow = (size_t)(base + row0 + row_local) * I_DIM;
      #pragma unroll
      for (int j = 0; j < 4; ++j) {
        float g = acc[i][j][r];
        float u = acc[i][j + 4][r];
        float s = g / (1.0f + __expf(-g)) * u;
        hb[orow + c0 + j * 16 + lr] = f2bf(s);
      }
    }
  }
}

// ---------------- GEMM B: out = h_e @ Wd_e (fp32 out) ----------------
// hb  : bf16 [T][I], wdT : bf16 [E][H][I]   (K-contiguous), out: fp32 [T][H]
__launch_bounds__(256, 2)
__global__ void k_gemm_b(const unsigned short* __restrict__ hb,
                         const unsigned short* __restrict__ wdT,
                         float* __restrict__ out,
                         const int* __restrict__ sched) {
  __shared__ unsigned short As[BM * BK];
  __shared__ unsigned short Bs[BM * BK];

  const int nt = sched[17];
  if ((int)blockIdx.y >= nt) return;
  const int e    = sched[18 + 2 * blockIdx.y];
  const int row0 = sched[19 + 2 * blockIdx.y];
  const int base = sched[e];
  const int cnt  = sched[e + 1] - base;
  const int rows = (cnt - row0 < BM) ? (cnt - row0) : BM;
  const int n0   = blockIdx.x * 128;       // out-column base

  const int tid = threadIdx.x;
  const int w = tid >> 6, l = tid & 63;
  const int lr = l & 15, q = l >> 4;
  const int srow = l >> 2;
  const int skc  = (l & 3) * 8;

  floatx4 acc[2][8];
  #pragma unroll
  for (int i = 0; i < 2; ++i)
    #pragma unroll
    for (int j = 0; j < 8; ++j) acc[i][j] = (floatx4){0.f, 0.f, 0.f, 0.f};

  const unsigned short* wd = wdT + (size_t)e * H_DIM * I_DIM;

  for (int kk = 0; kk < I_DIM; kk += BK) {
    #pragma unroll
    for (int c = 0; c < 2; ++c) {
      const int r = w * 32 + c * 16;
      int arow = r + srow;
      int gr = arow < rows ? arow : rows - 1;
      gld16(&hb[(size_t)(base + row0 + gr) * I_DIM + kk + skc], &As[r * BK]);
      int brow = r + srow;
      gld16(&wd[(size_t)(n0 + brow) * I_DIM + kk + skc], &Bs[r * BK]);
    }
    __syncthreads();

    bf16x8 af[2];
    #pragma unroll
    for (int i = 0; i < 2; ++i)
      af[i] = *(const bf16x8*)&As[(w * 32 + i * 16 + lr) * BK + q * 8];
    #pragma unroll
    for (int j = 0; j < 8; ++j) {
      bf16x8 bfj = *(const bf16x8*)&Bs[(j * 16 + lr) * BK + q * 8];
      acc[0][j] = __builtin_amdgcn_mfma_f32_16x16x32_bf16(af[0], bfj, acc[0][j], 0, 0, 0);
      acc[1][j] = __builtin_amdgcn_mfma_f32_16x16x32_bf16(af[1], bfj, acc[1][j], 0, 0, 0);
    }
    __syncthreads();
  }

  #pragma unroll
  for (int i = 0; i < 2; ++i) {
    const int rl = w * 32 + i * 16 + q * 4;
    #pragma unroll
    for (int r = 0; r < 4; ++r) {
      const int row_local = rl + r;
      if (row_local >= rows) continue;
      const size_t orow = (size_t)(base + row0 + row_local) * H_DIM;
      #pragma unroll
      for (int j = 0; j < 8; ++j)
        out[orow + n0 + j * 16 + lr] = acc[i][j][r];
    }
  }
}

// ---------------- launch ----------------
extern "C" void kernel_launch(void* const* d_in, const int* in_sizes, int n_in,
                              void* d_out, int out_size, void* d_ws, size_t ws_size,
                              hipStream_t stream) {
  const float* x      = (const float*)d_in[0];
  const float* wgu    = (const float*)d_in[1];
  const float* wdn    = (const float*)d_in[2];
  const int*   counts = (const int*)d_in[3];
  float* out = (float*)d_out;

  unsigned char* ws = (unsigned char*)d_ws;
  // layout: xb 8MB | wguT 32MB | wdT 16MB | h 4MB | sched
  unsigned short* xb   = (unsigned short*)(ws);
  unsigned short* wguT = (unsigned short*)(ws + 8388608);
  unsigned short* wdT  = (unsigned short*)(ws + 41943040);
  unsigned short* hb   = (unsigned short*)(ws + 58720256);
  int*            sched = (int*)(ws + 62914560);

  k_sched<<<1, 64, 0, stream>>>(counts, sched);
  k_cvt<<<(T_TOK * H_DIM / 4 + 255) / 256, 256, 0, stream>>>(x, xb, T_TOK * H_DIM / 4);
  k_tcvt<<<dim3(2 * I_DIM / 64, H_DIM / 64, E_EXP), dim3(64, 4), 0, stream>>>(wgu, wguT, H_DIM, 2 * I_DIM);
  k_tcvt<<<dim3(H_DIM / 64, I_DIM / 64, E_EXP), dim3(64, 4), 0, stream>>>(wdn, wdT, I_DIM, H_DIM);
  k_gemm_a<<<dim3(I_DIM / 64, 48), 256, 0, stream>>>(xb, wguT, hb, sched);
  k_gemm_b<<<dim3(H_DIM / 128, 48), 256, 0, stream>>>(hb, wdT, out, sched);
}

// Round 2
// 191.226 us; speedup vs baseline: 1.0729x; 1.0729x over previous
//
#include <hip/hip_runtime.h>
#include <hip/hip_bf16.h>

#define T_TOK 4096
#define H_DIM 1024
#define I_DIM 512
#define E_EXP 16
#define BM    64
#define BK    32

using bf16x8   = __attribute__((ext_vector_type(8))) short;
using floatx4  = __attribute__((ext_vector_type(4))) float;
using ushort4v = __attribute__((ext_vector_type(4))) unsigned short;

__device__ __forceinline__ unsigned short f2bf(float f) {
  union { float f; unsigned u; } v; v.f = f;
  return (unsigned short)((v.u + 0x7FFFu + ((v.u >> 16) & 1u)) >> 16);  // RNE
}

__device__ __forceinline__ void gld16(const void* g, void* l) {
  __builtin_amdgcn_global_load_lds((const __attribute__((address_space(1))) void*)g,
                                   (__attribute__((address_space(3))) void*)l,
                                   16, 0, 0);
}

// Derive this block's tile (expert, row0, base, cnt) from counts. Uniform
// scalar work (~16 iterations of cached loads) — replaces the k_sched kernel.
__device__ __forceinline__ bool tile_info(const int* __restrict__ counts, int by,
                                          int& e, int& row0, int& base, int& cnt) {
  int acc = 0, off = 0;
  e = -1;
  #pragma unroll
  for (int i = 0; i < E_EXP; ++i) {
    int c = counts[i];
    int nt = (c + BM - 1) >> 6;
    if (e < 0 && by < acc + nt) { e = i; row0 = (by - acc) * BM; base = off; cnt = c; }
    acc += nt; off += c;
  }
  return e >= 0;
}

// ---------------- fused prep: x cvt + wgu transpose-cvt + wd transpose-cvt ----------------
// block id partition: [0,4096) x-cvt | [4096,8192) wgu | [8192,10240) wd
__global__ void k_prep(const float* __restrict__ x, const float* __restrict__ wgu,
                       const float* __restrict__ wdn,
                       unsigned short* __restrict__ xb, unsigned short* __restrict__ wguT,
                       unsigned short* __restrict__ wdT) {
  __shared__ unsigned short tile[64][65];
  const int bid = blockIdx.x;
  const int tid = threadIdx.x;

  if (bid < 4096) {                      // ---- x: fp32 -> bf16, float4 ----
    int i = bid * 256 + tid;             // 4096*256*4 = 4M elems exactly
    float4 v = ((const float4*)x)[i];
    ushort4v o;
    o.x = f2bf(v.x); o.y = f2bf(v.y); o.z = f2bf(v.z); o.w = f2bf(v.w);
    ((ushort4v*)xb)[i] = o;
    return;
  }

  const float* src; unsigned short* dst; int R, C, bx, by;
  if (bid < 8192) {                      // ---- wgu: [H][2I] -> [2I][H] per expert ----
    int local = bid - 4096;
    int e = local >> 8, rem = local & 255;
    bx = rem & 15; by = rem >> 4;        // 16 x 16 tiles of 64x64
    R = H_DIM; C = 2 * I_DIM;
    src = wgu + (size_t)e * R * C;
    dst = wguT + (size_t)e * R * C;
  } else {                               // ---- wd: [I][H] -> [H][I] per expert ----
    int local = bid - 8192;
    int e = local >> 7, rem = local & 127;
    bx = rem & 15; by = rem >> 4;        // 16 x 8 tiles of 64x64
    R = I_DIM; C = H_DIM;
    src = wdn + (size_t)e * R * C;
    dst = wdT + (size_t)e * R * C;
  }
  const int c0 = bx * 64, r0 = by * 64;
  const int tx = tid & 63, ty = tid >> 6;
  #pragma unroll
  for (int rr = ty; rr < 64; rr += 4)
    tile[rr][tx] = f2bf(src[(size_t)(r0 + rr) * C + c0 + tx]);
  __syncthreads();
  #pragma unroll
  for (int cc = ty; cc < 64; cc += 4)
    dst[(size_t)(c0 + cc) * R + r0 + tx] = tile[tx][cc];
}

// ---------------- GEMM A: gu = x_e @ Wgu_e, h = silu(g)*u (bf16 out) ----------------
// 64-row tile x (64 g-cols + 64 u-cols). 4 waves, each: 16 rows x 128 B-rows.
__launch_bounds__(256, 4)
__global__ void k_gemm_a(const unsigned short* __restrict__ xb,
                         const unsigned short* __restrict__ wguT,
                         unsigned short* __restrict__ hb,
                         const int* __restrict__ counts) {
  __shared__ unsigned short As[BM * BK];     // 64 rows x 32 k
  __shared__ unsigned short Bs[128 * BK];    // rows 0..63 g-cols, 64..127 u-cols

  int e, row0, base, cnt;
  if (!tile_info(counts, blockIdx.y, e, row0, base, cnt)) return;
  const int rows = (cnt - row0 < BM) ? (cnt - row0) : BM;
  const int c0 = blockIdx.x * 64;            // g-column base within I

  const int tid = threadIdx.x;
  const int w = tid >> 6, l = tid & 63;
  const int lr = l & 15, q = l >> 4;
  const int sr = l >> 2;                     // staging: 4 lanes per 64B k-row
  const int skc = (l & 3) * 8;

  floatx4 acc[8];
  #pragma unroll
  for (int j = 0; j < 8; ++j) acc[j] = (floatx4){0.f, 0.f, 0.f, 0.f};

  const unsigned short* wg = wguT + (size_t)e * (2 * I_DIM) * H_DIM;

  for (int kk = 0; kk < H_DIM; kk += BK) {
    // A: one round — wave w stages rows [w*16, w*16+16)
    {
      int ar = w * 16 + sr;
      int gr = ar < rows ? ar : rows - 1;
      gld16(&xb[(size_t)(base + row0 + gr) * H_DIM + kk + skc], &As[(w * 16) * BK]);
    }
    // B: two rounds — g rows then u rows
    {
      int wrow = c0 + w * 16 + sr;                       // g
      gld16(&wg[(size_t)wrow * H_DIM + kk + skc], &Bs[(w * 16) * BK]);
      wrow = I_DIM + c0 + w * 16 + sr;                   // u
      gld16(&wg[(size_t)wrow * H_DIM + kk + skc], &Bs[(64 + w * 16) * BK]);
    }
    __syncthreads();

    bf16x8 af = *(const bf16x8*)&As[(w * 16 + lr) * BK + q * 8];
    #pragma unroll
    for (int j = 0; j < 8; ++j) {
      bf16x8 bfj = *(const bf16x8*)&Bs[(j * 16 + lr) * BK + q * 8];
      acc[j] = __builtin_amdgcn_mfma_f32_16x16x32_bf16(af, bfj, acc[j], 0, 0, 0);
    }
    __syncthreads();
  }

  // epilogue: h = silu(g)*u ; C/D: col=lane&15, row=q*4+reg
  const int rl = w * 16 + q * 4;
  #pragma unroll
  for (int r = 0; r < 4; ++r) {
    const int row_local = rl + r;
    if (row_local >= rows) continue;
    const size_t orow = (size_t)(base + row0 + row_local) * I_DIM;
    #pragma unroll
    for (int j = 0; j < 4; ++j) {
      float g = acc[j][r];
      float u = acc[j + 4][r];
      float s = g / (1.0f + __expf(-g)) * u;
      hb[orow + c0 + j * 16 + lr] = f2bf(s);
    }
  }
}

// ---------------- GEMM B: out = h_e @ Wd_e (fp32 out) ----------------
__launch_bounds__(256, 4)
__global__ void k_gemm_b(const unsigned short* __restrict__ hb,
                         const unsigned short* __restrict__ wdT,
                         float* __restrict__ out,
                         const int* __restrict__ counts) {
  __shared__ unsigned short As[BM * BK];
  __shared__ unsigned short Bs[128 * BK];

  int e, row0, base, cnt;
  if (!tile_info(counts, blockIdx.y, e, row0, base, cnt)) return;
  const int rows = (cnt - row0 < BM) ? (cnt - row0) : BM;
  const int n0 = blockIdx.x * 128;           // out-column base

  const int tid = threadIdx.x;
  const int w = tid >> 6, l = tid & 63;
  const int lr = l & 15, q = l >> 4;
  const int sr = l >> 2;
  const int skc = (l & 3) * 8;

  floatx4 acc[8];
  #pragma unroll
  for (int j = 0; j < 8; ++j) acc[j] = (floatx4){0.f, 0.f, 0.f, 0.f};

  const unsigned short* wd = wdT + (size_t)e * H_DIM * I_DIM;

  for (int kk = 0; kk < I_DIM; kk += BK) {
    {
      int ar = w * 16 + sr;
      int gr = ar < rows ? ar : rows - 1;
      gld16(&hb[(size_t)(base + row0 + gr) * I_DIM + kk + skc], &As[(w * 16) * BK]);
    }
    {
      int wrow = n0 + w * 16 + sr;
      gld16(&wd[(size_t)wrow * I_DIM + kk + skc], &Bs[(w * 16) * BK]);
      wrow = n0 + 64 + w * 16 + sr;
      gld16(&wd[(size_t)wrow * I_DIM + kk + skc], &Bs[(64 + w * 16) * BK]);
    }
    __syncthreads();

    bf16x8 af = *(const bf16x8*)&As[(w * 16 + lr) * BK + q * 8];
    #pragma unroll
    for (int j = 0; j < 8; ++j) {
      bf16x8 bfj = *(const bf16x8*)&Bs[(j * 16 + lr) * BK + q * 8];
      acc[j] = __builtin_amdgcn_mfma_f32_16x16x32_bf16(af, bfj, acc[j], 0, 0, 0);
    }
    __syncthreads();
  }

  const int rl = w * 16 + q * 4;
  #pragma unroll
  for (int r = 0; r < 4; ++r) {
    const int row_local = rl + r;
    if (row_local >= rows) continue;
    const size_t orow = (size_t)(base + row0 + row_local) * H_DIM;
    #pragma unroll
    for (int j = 0; j < 8; ++j)
      out[orow + n0 + j * 16 + lr] = acc[j][r];
  }
}

// ---------------- launch ----------------
extern "C" void kernel_launch(void* const* d_in, const int* in_sizes, int n_in,
                              void* d_out, int out_size, void* d_ws, size_t ws_size,
                              hipStream_t stream) {
  const float* x      = (const float*)d_in[0];
  const float* wgu    = (const float*)d_in[1];
  const float* wdn    = (const float*)d_in[2];
  const int*   counts = (const int*)d_in[3];
  float* out = (float*)d_out;

  unsigned char* ws = (unsigned char*)d_ws;
  // layout: xb 8MB | wguT 32MB | wdT 16MB | h 4MB
  unsigned short* xb   = (unsigned short*)(ws);
  unsigned short* wguT = (unsigned short*)(ws + 8388608);
  unsigned short* wdT  = (unsigned short*)(ws + 41943040);
  unsigned short* hb   = (unsigned short*)(ws + 58720256);

  k_prep<<<10240, 256, 0, stream>>>(x, wgu, wdn, xb, wguT, wdT);
  // grid.y = 80 provably covers sum(ceil(c_e/64)) <= 4096/64 + 16 = 80
  k_gemm_a<<<dim3(I_DIM / 64, 80), 256, 0, stream>>>(xb, wguT, hb, counts);
  k_gemm_b<<<dim3(H_DIM / 128, 80), 256, 0, stream>>>(hb, wdT, out, counts);
}

// Round 3
// 185.152 us; speedup vs baseline: 1.1081x; 1.0328x over previous
//
#include <hip/hip_runtime.h>
#include <hip/hip_bf16.h>

#define T_TOK 4096
#define H_DIM 1024
#define I_DIM 512
#define E_EXP 16
#define BM    64
#define BK    64   // k elems (bf16) per barrier step

using bf16x8   = __attribute__((ext_vector_type(8))) short;
using floatx16 = __attribute__((ext_vector_type(16))) float;
using ushort4v = __attribute__((ext_vector_type(4))) unsigned short;
using ushort8v = __attribute__((ext_vector_type(8))) unsigned short;

__device__ __forceinline__ unsigned short f2bf(float f) {
  union { float f; unsigned u; } v; v.f = f;
  return (unsigned short)((v.u + 0x7FFFu + ((v.u >> 16) & 1u)) >> 16);  // RNE
}

__device__ __forceinline__ void gld16(const void* g, void* l) {
  __builtin_amdgcn_global_load_lds((const __attribute__((address_space(1))) void*)g,
                                   (__attribute__((address_space(3))) void*)l,
                                   16, 0, 0);
}

__device__ __forceinline__ bool tile_info(const int* __restrict__ counts, int by,
                                          int& e, int& row0, int& base, int& cnt) {
  int acc = 0, off = 0;
  e = -1;
  #pragma unroll
  for (int i = 0; i < E_EXP; ++i) {
    int c = counts[i];
    int nt = (c + BM - 1) >> 6;
    if (e < 0 && by < acc + nt) { e = i; row0 = (by - acc) * BM; base = off; cnt = c; }
    acc += nt; off += c;
  }
  return e >= 0;
}

// ---------------- fused prep ----------------
// blocks: [0,2048) x-cvt (512 float4 each) | [2048,6144) wgu tiles | [6144,8192) wd tiles
__global__ void k_prep(const float* __restrict__ x, const float* __restrict__ wgu,
                       const float* __restrict__ wdn,
                       unsigned short* __restrict__ xb, unsigned short* __restrict__ wguT,
                       unsigned short* __restrict__ wdT) {
  __shared__ unsigned short tT[64 * 68];   // [col][row], pad 4 -> 2-way max on reads
  const int bid = blockIdx.x, tid = threadIdx.x;

  if (bid < 2048) {                        // ---- x: fp32 -> bf16, 2 batched float4 ----
    const float4* s4 = (const float4*)x;
    int base = bid * 512 + tid;
    float4 a = s4[base];                   // independent loads: both in flight
    float4 b = s4[base + 256];
    ushort4v oa, ob;
    oa.x = f2bf(a.x); oa.y = f2bf(a.y); oa.z = f2bf(a.z); oa.w = f2bf(a.w);
    ob.x = f2bf(b.x); ob.y = f2bf(b.y); ob.z = f2bf(b.z); ob.w = f2bf(b.w);
    ((ushort4v*)xb)[base] = oa;
    ((ushort4v*)xb)[base + 256] = ob;
    return;
  }

  const float* src; unsigned short* dst; int R, C, bx, by;
  if (bid < 6144) {                        // wgu [H][2I] -> [2I][H] per expert
    int local = bid - 2048;
    int e = local >> 8, rem = local & 255;
    bx = rem & 15; by = rem >> 4;          // 16 x 16 tiles
    R = H_DIM; C = 2 * I_DIM;
    src = wgu + (size_t)e * R * C;
    dst = wguT + (size_t)e * R * C;
  } else {                                 // wd [I][H] -> [H][I] per expert
    int local = bid - 6144;
    int e = local >> 7, rem = local & 127;
    bx = rem & 15; by = rem >> 4;          // 16 x 8 tiles
    R = I_DIM; C = H_DIM;
    src = wdn + (size_t)e * R * C;
    dst = wdT + (size_t)e * R * C;
  }
  const int c0 = bx * 64, r0 = by * 64;

  // load phase: 4 batched float4 loads -> registers (forces 4 outstanding / thread)
  float4 v[4]; int rw[4], cb[4];
  #pragma unroll
  for (int it = 0; it < 4; ++it) {
    int flat = it * 256 + tid;
    rw[it] = flat >> 4;                    // row within tile
    cb[it] = flat & 15;                    // float4-chunk within 64 cols
    v[it] = ((const float4*)(src + (size_t)(r0 + rw[it]) * C + c0))[cb[it]];
  }
  // scatter transposed into LDS (b16 writes; conflicts hidden under load latency)
  #pragma unroll
  for (int it = 0; it < 4; ++it) {
    int c = cb[it] * 4, r = rw[it];
    tT[(c + 0) * 68 + r] = f2bf(v[it].x);
    tT[(c + 1) * 68 + r] = f2bf(v[it].y);
    tT[(c + 2) * 68 + r] = f2bf(v[it].z);
    tT[(c + 3) * 68 + r] = f2bf(v[it].w);
  }
  __syncthreads();
  // store phase: contiguous 16B stores, 2-way-max LDS reads
  #pragma unroll
  for (int it = 0; it < 2; ++it) {
    int s = it * 256 + tid;
    int cc = s >> 3, r8 = s & 7;
    const unsigned short* p = &tT[cc * 68 + r8 * 8];
    ushort4v a = *(const ushort4v*)p;
    ushort4v b = *(const ushort4v*)(p + 4);
    ushort8v o = __builtin_shufflevector(a, b, 0, 1, 2, 3, 4, 5, 6, 7);
    *(ushort8v*)&dst[(size_t)(c0 + cc) * R + r0 + r8 * 8] = o;
  }
}

// ---------------- GEMM A: h = silu(x@Wg) * (x@Wu), bf16 out ----------------
// tile: 64 tokens x (64 g-cols + 64 u-cols); 4 waves = 2(m) x 2(n) of 32x32 MFMA
__launch_bounds__(256, 4)
__global__ void k_gemm_a(const unsigned short* __restrict__ xb,
                         const unsigned short* __restrict__ wguT,
                         unsigned short* __restrict__ hb,
                         const int* __restrict__ counts) {
  __shared__ unsigned short As[64 * BK];    // xor-swizzled 16B chunks
  __shared__ unsigned short Bs[128 * BK];   // rows 0..63 g, 64..127 u

  int e, row0, base, cnt;
  if (!tile_info(counts, blockIdx.y, e, row0, base, cnt)) return;
  const int rows = (cnt - row0 < BM) ? (cnt - row0) : BM;
  const int c0 = blockIdx.x * 64;

  const int tid = threadIdx.x;
  const int w = tid >> 6, l = tid & 63;
  const int ml = l & 31, gh = l >> 5;       // frag lane row/col, k-group
  const int sr = l >> 3, sc = l & 7;        // staging row-in-8, phys chunk
  const int scs = (sc ^ sr) * 8;            // swizzled logical k-offset (elems)
  const int m7 = ml & 7;

  floatx16 ag = {0}, au = {0};
  const unsigned short* wg = wguT + (size_t)e * (2 * I_DIM) * H_DIM;
  const int mrow = (w & 1) * 32;            // wave m-half
  const int nrow = (w >> 1) * 32;           // wave n-half

  for (int kk = 0; kk < H_DIM; kk += BK) {
    #pragma unroll
    for (int i = 0; i < 2; ++i) {           // A: 16 rows per wave
      int r = w * 16 + i * 8 + sr;
      int gr = r < rows ? r : rows - 1;
      gld16(&xb[(size_t)(base + row0 + gr) * H_DIM + kk + scs], &As[(w * 16 + i * 8) * BK]);
    }
    #pragma unroll
    for (int i = 0; i < 4; ++i) {           // B: 32 rows per wave
      int nb = w * 32 + i * 8 + sr;
      int wrow = (nb < 64) ? (c0 + nb) : (I_DIM + c0 + (nb - 64));
      gld16(&wg[(size_t)wrow * H_DIM + kk + scs], &Bs[(w * 32 + i * 8) * BK]);
    }
    __syncthreads();

    #pragma unroll
    for (int ks = 0; ks < 4; ++ks) {
      const int ca = ks * 2 + gh;           // logical 8-elem chunk
      bf16x8 af = *(const bf16x8*)&As[(mrow + ml) * BK + ((ca ^ m7) * 8)];
      bf16x8 bg = *(const bf16x8*)&Bs[(nrow + ml) * BK + ((ca ^ m7) * 8)];
      bf16x8 bu = *(const bf16x8*)&Bs[(64 + nrow + ml) * BK + ((ca ^ m7) * 8)];
      ag = __builtin_amdgcn_mfma_f32_32x32x16_bf16(af, bg, ag, 0, 0, 0);
      au = __builtin_amdgcn_mfma_f32_32x32x16_bf16(af, bu, au, 0, 0, 0);
    }
    __syncthreads();
  }

  // C/D 32x32: col = lane&31, row = (reg&3) + 8*(reg>>2) + 4*(lane>>5)
  #pragma unroll
  for (int reg = 0; reg < 16; ++reg) {
    int rowf = (reg & 3) + 8 * (reg >> 2) + 4 * gh;
    int row_local = mrow + rowf;
    if (row_local >= rows) continue;
    float g = ag[reg], u = au[reg];
    float s = g / (1.0f + __expf(-g)) * u;
    hb[(size_t)(base + row0 + row_local) * I_DIM + c0 + nrow + ml] = f2bf(s);
  }
}

// ---------------- GEMM B: out = h @ Wd, fp32 out ----------------
// tile: 64 tokens x 128 out-cols; wave = 32m x 64n (2 frags)
__launch_bounds__(256, 4)
__global__ void k_gemm_b(const unsigned short* __restrict__ hb,
                         const unsigned short* __restrict__ wdT,
                         float* __restrict__ out,
                         const int* __restrict__ counts) {
  __shared__ unsigned short As[64 * BK];
  __shared__ unsigned short Bs[128 * BK];

  int e, row0, base, cnt;
  if (!tile_info(counts, blockIdx.y, e, row0, base, cnt)) return;
  const int rows = (cnt - row0 < BM) ? (cnt - row0) : BM;
  const int n0 = blockIdx.x * 128;

  const int tid = threadIdx.x;
  const int w = tid >> 6, l = tid & 63;
  const int ml = l & 31, gh = l >> 5;
  const int sr = l >> 3, sc = l & 7;
  const int scs = (sc ^ sr) * 8;
  const int m7 = ml & 7;

  floatx16 acc0 = {0}, acc1 = {0};
  const unsigned short* wd = wdT + (size_t)e * H_DIM * I_DIM;
  const int mrow = (w & 1) * 32;
  const int nrow = (w >> 1) * 64;

  for (int kk = 0; kk < I_DIM; kk += BK) {
    #pragma unroll
    for (int i = 0; i < 2; ++i) {
      int r = w * 16 + i * 8 + sr;
      int gr = r < rows ? r : rows - 1;
      gld16(&hb[(size_t)(base + row0 + gr) * I_DIM + kk + scs], &As[(w * 16 + i * 8) * BK]);
    }
    #pragma unroll
    for (int i = 0; i < 4; ++i) {
      int nb = w * 32 + i * 8 + sr;
      gld16(&wd[(size_t)(n0 + nb) * I_DIM + kk + scs], &Bs[(w * 32 + i * 8) * BK]);
    }
    __syncthreads();

    #pragma unroll
    for (int ks = 0; ks < 4; ++ks) {
      const int ca = ks * 2 + gh;
      bf16x8 af = *(const bf16x8*)&As[(mrow + ml) * BK + ((ca ^ m7) * 8)];
      bf16x8 b0 = *(const bf16x8*)&Bs[(nrow + ml) * BK + ((ca ^ m7) * 8)];
      bf16x8 b1 = *(const bf16x8*)&Bs[(nrow + 32 + ml) * BK + ((ca ^ m7) * 8)];
      acc0 = __builtin_amdgcn_mfma_f32_32x32x16_bf16(af, b0, acc0, 0, 0, 0);
      acc1 = __builtin_amdgcn_mfma_f32_32x32x16_bf16(af, b1, acc1, 0, 0, 0);
    }
    __syncthreads();
  }

  #pragma unroll
  for (int reg = 0; reg < 16; ++reg) {
    int rowf = (reg & 3) + 8 * (reg >> 2) + 4 * gh;
    int row_local = mrow + rowf;
    if (row_local >= rows) continue;
    const size_t orow = (size_t)(base + row0 + row_local) * H_DIM;
    out[orow + n0 + nrow + ml] = acc0[reg];
    out[orow + n0 + nrow + 32 + ml] = acc1[reg];
  }
}

// ---------------- launch ----------------
extern "C" void kernel_launch(void* const* d_in, const int* in_sizes, int n_in,
                              void* d_out, int out_size, void* d_ws, size_t ws_size,
                              hipStream_t stream) {
  const float* x      = (const float*)d_in[0];
  const float* wgu    = (const float*)d_in[1];
  const float* wdn    = (const float*)d_in[2];
  const int*   counts = (const int*)d_in[3];
  float* out = (float*)d_out;

  unsigned char* ws = (unsigned char*)d_ws;
  unsigned short* xb   = (unsigned short*)(ws);
  unsigned short* wguT = (unsigned short*)(ws + 8388608);
  unsigned short* wdT  = (unsigned short*)(ws + 41943040);
  unsigned short* hb   = (unsigned short*)(ws + 58720256);

  k_prep<<<8192, 256, 0, stream>>>(x, wgu, wdn, xb, wguT, wdT);
  k_gemm_a<<<dim3(I_DIM / 64, 80), 256, 0, stream>>>(xb, wguT, hb, counts);
  k_gemm_b<<<dim3(H_DIM / 128, 80), 256, 0, stream>>>(hb, wdT, out, counts);
}

// Round 4
// 183.475 us; speedup vs baseline: 1.1182x; 1.0091x over previous
//
#include <hip/hip_runtime.h>
#include <hip/hip_bf16.h>

#define T_TOK 4096
#define H_DIM 1024
#define I_DIM 512
#define E_EXP 16
#define BM    128
#define BK    64

using bf16x8  = __attribute__((ext_vector_type(8))) short;
using floatx4 = __attribute__((ext_vector_type(4))) float;
using ushort4v = __attribute__((ext_vector_type(4))) unsigned short;

__device__ __forceinline__ unsigned short f2bf(float f) {
  union { float f; unsigned u; } v; v.f = f;
  return (unsigned short)((v.u + 0x7FFFu + ((v.u >> 16) & 1u)) >> 16);  // RNE
}

__device__ __forceinline__ void gld16(const void* g, void* l) {
  __builtin_amdgcn_global_load_lds((const __attribute__((address_space(1))) void*)g,
                                   (__attribute__((address_space(3))) void*)l,
                                   16, 0, 0);
}

__device__ __forceinline__ bool tile_info(const int* __restrict__ counts, int by,
                                          int& e, int& row0, int& base, int& cnt) {
  int acc = 0, off = 0;
  e = -1;
  #pragma unroll
  for (int i = 0; i < E_EXP; ++i) {
    int c = counts[i];
    int nt = (c + BM - 1) >> 7;
    if (e < 0 && by < acc + nt) { e = i; row0 = (by - acc) * BM; base = off; cnt = c; }
    acc += nt; off += c;
  }
  return e >= 0;
}

// ---------------- fused prep ----------------
// [0,4096) wgu transpose | [4096,6144) wd transpose | [6144,8192) x cvt
__global__ void k_prep(const float* __restrict__ x, const float* __restrict__ wgu,
                       const float* __restrict__ wdn,
                       unsigned short* __restrict__ xb, unsigned short* __restrict__ wguT,
                       unsigned short* __restrict__ wdT) {
  __shared__ unsigned int tT[64 * 34];     // [n][k-pair dword], stride 34
  const int bid = blockIdx.x, tid = threadIdx.x;

  if (bid >= 6144) {                       // ---- x: fp32 -> bf16 ----
    const float4* s4 = (const float4*)x;
    int b0 = (bid - 6144) * 512 + tid;
    float4 a = s4[b0];
    float4 b = s4[b0 + 256];
    ushort4v oa, ob;
    oa.x = f2bf(a.x); oa.y = f2bf(a.y); oa.z = f2bf(a.z); oa.w = f2bf(a.w);
    ob.x = f2bf(b.x); ob.y = f2bf(b.y); ob.z = f2bf(b.z); ob.w = f2bf(b.w);
    ((ushort4v*)xb)[b0] = oa;
    ((ushort4v*)xb)[b0 + 256] = ob;
    return;
  }

  const float* src; unsigned short* dst; int R, C, kb, nb;
  if (bid < 4096) {                        // wgu [1024 k][1024 n] -> [n][k]
    int e = bid >> 8, rem = bid & 255;
    kb = rem >> 4; nb = rem & 15;
    R = H_DIM; C = 2 * I_DIM;
    src = wgu + (size_t)e * R * C;
    dst = wguT + (size_t)e * R * C;
  } else {                                 // wd [512 k][1024 n] -> [n][k]
    int local = bid - 4096;
    int e = local >> 7, rem = local & 127;
    kb = rem >> 4; nb = rem & 15;          // 8 x 16 tiles
    R = I_DIM; C = H_DIM;
    src = wdn + (size_t)e * R * C;
    dst = wdT + (size_t)e * R * C;
  }
  const int r0 = kb * 64, c0 = nb * 64;
  const int w = tid >> 6, l = tid & 63;
  const int n0 = (l & 15) * 4;
  const int ksub = l >> 4;                 // 0..3

  // load phase: 4 independent float4 loads (row pairs k, k+1)
  float4 v0[2], v1[2];
  #pragma unroll
  for (int it = 0; it < 2; ++it) {
    int kp = w * 8 + it * 4 + ksub;        // k-pair 0..31
    const float* p = src + (size_t)(r0 + kp * 2) * C + c0 + n0;
    v0[it] = *(const float4*)p;
    v1[it] = *(const float4*)(p + C);
  }
  // pack bf16 pairs -> dword, write LDS (stride 34 dw: <=4-way)
  #pragma unroll
  for (int it = 0; it < 2; ++it) {
    int kp = w * 8 + it * 4 + ksub;
    const float* a = (const float*)&v0[it];
    const float* b = (const float*)&v1[it];
    #pragma unroll
    for (int j = 0; j < 4; ++j)
      tT[(n0 + j) * 34 + kp] = (unsigned)f2bf(a[j]) | ((unsigned)f2bf(b[j]) << 16);
  }
  __syncthreads();
  // store phase: 16B coalesced stores, b64 LDS reads (<=2-way)
  #pragma unroll
  for (int it = 0; it < 2; ++it) {
    int cidx = it * 256 + tid;             // 512 16B-chunks
    int n = cidx >> 3, ck = cidx & 7;
    const unsigned int* p = &tT[n * 34 + ck * 4];
    uint2 a = *(const uint2*)p;
    uint2 b = *(const uint2*)(p + 2);
    uint4 o = {a.x, a.y, b.x, b.y};
    *(uint4*)&dst[(size_t)(c0 + n) * R + r0 + ck * 8] = o;
  }
}

// ---------------- GEMM A: h = silu(x@Wg)*(x@Wu), bf16 out ----------------
// block: 128 tokens x (64 g + 64 u); waves 2x2, wave = 64m x (32g+32u)
// dbuf LDS; stage(buf^1) issued AFTER barrier -> vmcnt drain has full compute phase
__launch_bounds__(256, 2)
__global__ void k_gemm_a(const unsigned short* __restrict__ xb,
                         const unsigned short* __restrict__ wguT,
                         unsigned short* __restrict__ hb,
                         const int* __restrict__ counts) {
  __shared__ unsigned short As[2][BM * BK];   // 32 KB
  __shared__ unsigned short Bs[2][BM * BK];   // 32 KB (rows 0-63 g, 64-127 u)

  int e, row0, base, cnt;
  if (!tile_info(counts, blockIdx.y, e, row0, base, cnt)) return;
  const int rows = (cnt - row0 < BM) ? (cnt - row0) : BM;
  const int c0 = blockIdx.x * 64;

  const int tid = threadIdx.x;
  const int w = tid >> 6, l = tid & 63;
  const int lr = l & 15, q = l >> 4;
  const int sr = l >> 3, sc = l & 7;
  const int lc = (sc ^ sr) * 8;              // swizzled logical k-offset for staging
  const int key = lr & 7;
  const int mhalf = w & 1, nhalf = w >> 1;
  const int mrow = mhalf * 64;

  floatx4 accg[4][2], accu[4][2];
  #pragma unroll
  for (int i = 0; i < 4; ++i)
    #pragma unroll
    for (int j = 0; j < 2; ++j) { accg[i][j] = (floatx4){0,0,0,0}; accu[i][j] = (floatx4){0,0,0,0}; }

  const unsigned short* wg = wguT + (size_t)e * (2 * I_DIM) * H_DIM;

  #define STAGE_A(buf, kk)                                                        \
    _Pragma("unroll")                                                             \
    for (int t = 0; t < 4; ++t) {                                                 \
      int rb = w * 32 + t * 8 + sr;                                               \
      int gr = rb < rows ? rb : rows - 1;                                         \
      gld16(&xb[(size_t)(base + row0 + gr) * H_DIM + (kk) + lc],                  \
            &As[buf][(w * 32 + t * 8) * BK]);                                     \
      int wrow = rb < 64 ? c0 + rb : I_DIM + c0 + (rb - 64);                      \
      gld16(&wg[(size_t)wrow * H_DIM + (kk) + lc],                                \
            &Bs[buf][(w * 32 + t * 8) * BK]);                                     \
    }

  STAGE_A(0, 0);
  const int nk = H_DIM / BK;                 // 16
  for (int ki = 0; ki < nk; ++ki) {
    const int buf = ki & 1;
    __syncthreads();                         // drains buf's staging loads
    if (ki + 1 < nk) { STAGE_A(buf ^ 1, (ki + 1) * BK); }
    #pragma unroll
    for (int kf = 0; kf < 2; ++kf) {
      const int ch = ((kf * 4 + q) ^ key) * 8;
      bf16x8 af[4], bg[2], bu[2];
      #pragma unroll
      for (int mi = 0; mi < 4; ++mi)
        af[mi] = *(const bf16x8*)&As[buf][(mrow + mi * 16 + lr) * BK + ch];
      #pragma unroll
      for (int ni = 0; ni < 2; ++ni) {
        bg[ni] = *(const bf16x8*)&Bs[buf][(nhalf * 32 + ni * 16 + lr) * BK + ch];
        bu[ni] = *(const bf16x8*)&Bs[buf][(64 + nhalf * 32 + ni * 16 + lr) * BK + ch];
      }
      #pragma unroll
      for (int mi = 0; mi < 4; ++mi)
        #pragma unroll
        for (int ni = 0; ni < 2; ++ni) {
          accg[mi][ni] = __builtin_amdgcn_mfma_f32_16x16x32_bf16(af[mi], bg[ni], accg[mi][ni], 0, 0, 0);
          accu[mi][ni] = __builtin_amdgcn_mfma_f32_16x16x32_bf16(af[mi], bu[ni], accu[mi][ni], 0, 0, 0);
        }
    }
  }
  #undef STAGE_A

  #pragma unroll
  for (int mi = 0; mi < 4; ++mi)
    #pragma unroll
    for (int r = 0; r < 4; ++r) {
      int row_local = mrow + mi * 16 + q * 4 + r;
      if (row_local >= rows) continue;
      size_t orow = (size_t)(base + row0 + row_local) * I_DIM;
      #pragma unroll
      for (int ni = 0; ni < 2; ++ni) {
        float g = accg[mi][ni][r], u = accu[mi][ni][r];
        float s = g / (1.0f + __expf(-g)) * u;
        hb[orow + c0 + nhalf * 32 + ni * 16 + lr] = f2bf(s);
      }
    }
}

// ---------------- GEMM B: out = h @ Wd, fp32 out ----------------
// block: 128 tokens x 128 cols; waves 2x2, wave = 64m x 64n
__launch_bounds__(256, 2)
__global__ void k_gemm_b(const unsigned short* __restrict__ hb,
                         const unsigned short* __restrict__ wdT,
                         float* __restrict__ out,
                         const int* __restrict__ counts) {
  __shared__ unsigned short As[2][BM * BK];
  __shared__ unsigned short Bs[2][BM * BK];

  int e, row0, base, cnt;
  if (!tile_info(counts, blockIdx.y, e, row0, base, cnt)) return;
  const int rows = (cnt - row0 < BM) ? (cnt - row0) : BM;
  const int n0 = blockIdx.x * 128;

  const int tid = threadIdx.x;
  const int w = tid >> 6, l = tid & 63;
  const int lr = l & 15, q = l >> 4;
  const int sr = l >> 3, sc = l & 7;
  const int lc = (sc ^ sr) * 8;
  const int key = lr & 7;
  const int mhalf = w & 1, nhalf = w >> 1;
  const int mrow = mhalf * 64;

  floatx4 acc[4][4];
  #pragma unroll
  for (int i = 0; i < 4; ++i)
    #pragma unroll
    for (int j = 0; j < 4; ++j) acc[i][j] = (floatx4){0,0,0,0};

  const unsigned short* wd = wdT + (size_t)e * H_DIM * I_DIM;

  #define STAGE_B(buf, kk)                                                        \
    _Pragma("unroll")                                                             \
    for (int t = 0; t < 4; ++t) {                                                 \
      int rb = w * 32 + t * 8 + sr;                                               \
      int gr = rb < rows ? rb : rows - 1;                                         \
      gld16(&hb[(size_t)(base + row0 + gr) * I_DIM + (kk) + lc],                  \
            &As[buf][(w * 32 + t * 8) * BK]);                                     \
      gld16(&wd[(size_t)(n0 + rb) * I_DIM + (kk) + lc],                           \
            &Bs[buf][(w * 32 + t * 8) * BK]);                                     \
    }

  STAGE_B(0, 0);
  const int nk = I_DIM / BK;                 // 8
  for (int ki = 0; ki < nk; ++ki) {
    const int buf = ki & 1;
    __syncthreads();
    if (ki + 1 < nk) { STAGE_B(buf ^ 1, (ki + 1) * BK); }
    #pragma unroll
    for (int kf = 0; kf < 2; ++kf) {
      const int ch = ((kf * 4 + q) ^ key) * 8;
      bf16x8 af[4], bf[4];
      #pragma unroll
      for (int mi = 0; mi < 4; ++mi)
        af[mi] = *(const bf16x8*)&As[buf][(mrow + mi * 16 + lr) * BK + ch];
      #pragma unroll
      for (int ni = 0; ni < 4; ++ni)
        bf[ni] = *(const bf16x8*)&Bs[buf][(nhalf * 64 + ni * 16 + lr) * BK + ch];
      #pragma unroll
      for (int mi = 0; mi < 4; ++mi)
        #pragma unroll
        for (int ni = 0; ni < 4; ++ni)
          acc[mi][ni] = __builtin_amdgcn_mfma_f32_16x16x32_bf16(af[mi], bf[ni], acc[mi][ni], 0, 0, 0);
    }
  }
  #undef STAGE_B

  #pragma unroll
  for (int mi = 0; mi < 4; ++mi)
    #pragma unroll
    for (int r = 0; r < 4; ++r) {
      int row_local = mrow + mi * 16 + q * 4 + r;
      if (row_local >= rows) continue;
      size_t orow = (size_t)(base + row0 + row_local) * H_DIM;
      #pragma unroll
      for (int ni = 0; ni < 4; ++ni)
        out[orow + n0 + nhalf * 64 + ni * 16 + lr] = acc[mi][ni][r];
    }
}

// ---------------- launch ----------------
extern "C" void kernel_launch(void* const* d_in, const int* in_sizes, int n_in,
                              void* d_out, int out_size, void* d_ws, size_t ws_size,
                              hipStream_t stream) {
  const float* x      = (const float*)d_in[0];
  const float* wgu    = (const float*)d_in[1];
  const float* wdn    = (const float*)d_in[2];
  const int*   counts = (const int*)d_in[3];
  float* out = (float*)d_out;

  unsigned char* ws = (unsigned char*)d_ws;
  unsigned short* xb   = (unsigned short*)(ws);
  unsigned short* wguT = (unsigned short*)(ws + 8388608);
  unsigned short* wdT  = (unsigned short*)(ws + 41943040);
  unsigned short* hb   = (unsigned short*)(ws + 58720256);

  k_prep<<<8192, 256, 0, stream>>>(x, wgu, wdn, xb, wguT, wdT);
  // grid.y = 48 covers sum(ceil(c_e/128)) <= 4096/128 + 16 = 48
  k_gemm_a<<<dim3(I_DIM / 64, 48), 256, 0, stream>>>(xb, wguT, hb, counts);
  k_gemm_b<<<dim3(H_DIM / 128, 48), 256, 0, stream>>>(hb, wdT, out, counts);
}

// Round 5
// 182.273 us; speedup vs baseline: 1.1256x; 1.0066x over previous
//
#include <hip/hip_runtime.h>
#include <hip/hip_bf16.h>

#define T_TOK 4096
#define H_DIM 1024
#define I_DIM 512
#define E_EXP 16
#define BM    128
#define BK    64
#define BSTR  68   // Bs row stride in shorts (64 + 4 pad -> 34 dwords, odd-ish banks)

using bf16x8   = __attribute__((ext_vector_type(8))) short;
using floatx4  = __attribute__((ext_vector_type(4))) float;
using ushort4v = __attribute__((ext_vector_type(4))) unsigned short;

__device__ __forceinline__ unsigned short f2bf(float f) {
  union { float f; unsigned u; } v; v.f = f;
  return (unsigned short)((v.u + 0x7FFFu + ((v.u >> 16) & 1u)) >> 16);  // RNE
}
__device__ __forceinline__ unsigned pk2(float a, float b) {
  return (unsigned)f2bf(a) | ((unsigned)f2bf(b) << 16);
}

__device__ __forceinline__ void gld16(const void* g, void* l) {
  __builtin_amdgcn_global_load_lds((const __attribute__((address_space(1))) void*)g,
                                   (__attribute__((address_space(3))) void*)l,
                                   16, 0, 0);
}

__device__ __forceinline__ bool tile_info(const int* __restrict__ counts, int by,
                                          int& e, int& row0, int& base, int& cnt) {
  int acc = 0, off = 0;
  e = -1;
  #pragma unroll
  for (int i = 0; i < E_EXP; ++i) {
    int c = counts[i];
    int nt = (c + BM - 1) >> 7;
    if (e < 0 && by < acc + nt) { e = i; row0 = (by - acc) * BM; base = off; cnt = c; }
    acc += nt; off += c;
  }
  return e >= 0;
}

// ---------------- x: fp32 -> bf16 (streaming) ----------------
__global__ void k_cvt(const float* __restrict__ x, unsigned short* __restrict__ xb) {
  const float4* s4 = (const float4*)x;
  int b0 = blockIdx.x * 512 + threadIdx.x;
  float4 a = s4[b0];
  float4 b = s4[b0 + 256];
  ushort4v oa, ob;
  oa.x = f2bf(a.x); oa.y = f2bf(a.y); oa.z = f2bf(a.z); oa.w = f2bf(a.w);
  ob.x = f2bf(b.x); ob.y = f2bf(b.y); ob.z = f2bf(b.z); ob.w = f2bf(b.w);
  ((ushort4v*)xb)[b0] = oa;
  ((ushort4v*)xb)[b0 + 256] = ob;
}

// ---------------- GEMM A: h = silu(x@Wg)*(x@Wu), fused W transpose-convert ----------------
// block: 128 tokens x (64 g + 64 u); waves 2m x 2n; wave = 64m x (32g+32u)
// A: xb bf16 via global_load_lds. B: wgu fp32 read per-column, cvt, LDS [n][k].
__launch_bounds__(256, 3)
__global__ void k_gemm_a(const unsigned short* __restrict__ xb,
                         const float* __restrict__ wgu,
                         unsigned short* __restrict__ hb,
                         const int* __restrict__ counts) {
  __shared__ unsigned short As[BM * BK];      // [m][k] 16 KB
  __shared__ unsigned short Bs[BM * BSTR];    // [n][k] stride 68, rows 0-63 g, 64-127 u

  int e, row0, base, cnt;
  if (!tile_info(counts, blockIdx.y, e, row0, base, cnt)) return;
  const int rows = (cnt - row0 < BM) ? (cnt - row0) : BM;
  const int c0 = blockIdx.x * 64;

  const int tid = threadIdx.x;
  const int w = tid >> 6, l = tid & 63;
  const int lr = l & 15, q = l >> 4;
  const int asr = l >> 3, akc = (l & 7) * 8;      // A staging: 8 rows/instr
  // B staging: this thread owns one transposed LDS row (column of W)
  const int nloc = ((w & 1) << 6) | l;            // 0..127
  const int kh = (w >> 1) * 32;                   // k-half within BK
  const int gcol = (nloc < 64) ? (c0 + nloc) : (I_DIM + c0 + (nloc - 64));
  const float* wcol = wgu + (size_t)e * H_DIM * (2 * I_DIM) + gcol;
  unsigned int* BsD = (unsigned int*)Bs;
  const int bdst = nloc * (BSTR / 2) + (kh >> 1); // dword base in Bs row

  const int mhalf = w & 1, nhalf = w >> 1;
  const int mrow = mhalf * 64;

  floatx4 accg[4][2], accu[4][2];
  #pragma unroll
  for (int i = 0; i < 4; ++i)
    #pragma unroll
    for (int j = 0; j < 2; ++j) { accg[i][j] = (floatx4){0,0,0,0}; accu[i][j] = (floatx4){0,0,0,0}; }

  const int nk = H_DIM / BK;   // 16
  for (int ki = 0; ki < nk; ++ki) {
    const int kk = ki * BK;
    // --- B loads: 32 independent dwords down this thread's column ---
    float bv[32];
    #pragma unroll
    for (int j = 0; j < 32; ++j)
      bv[j] = wcol[(size_t)(kk + kh + j) * (2 * I_DIM)];
    // --- A staging: 4 gld16 per wave ---
    #pragma unroll
    for (int t = 0; t < 4; ++t) {
      int r = w * 32 + t * 8 + asr;
      int gr = r < rows ? r : rows - 1;
      gld16(&xb[(size_t)(base + row0 + gr) * H_DIM + kk + akc], &As[(w * 32 + t * 8) * BK]);
    }
    // --- convert + transpose-write B: 8 b64 stores, ~2-way banks ---
    #pragma unroll
    for (int jq = 0; jq < 8; ++jq) {
      uint2 d;
      d.x = pk2(bv[4 * jq + 0], bv[4 * jq + 1]);
      d.y = pk2(bv[4 * jq + 2], bv[4 * jq + 3]);
      *(uint2*)&BsD[bdst + jq * 2] = d;
    }
    __syncthreads();
    // --- compute: 2 sub-steps x 16 MFMA ---
    #pragma unroll
    for (int kf = 0; kf < 2; ++kf) {
      const int ch = (kf * 4 + q) * 8;
      bf16x8 af[4], bg[2], bu[2];
      #pragma unroll
      for (int mi = 0; mi < 4; ++mi)
        af[mi] = *(const bf16x8*)&As[(mrow + mi * 16 + lr) * BK + ch];
      #pragma unroll
      for (int ni = 0; ni < 2; ++ni) {
        bg[ni] = *(const bf16x8*)&Bs[(nhalf * 32 + ni * 16 + lr) * BSTR + ch];
        bu[ni] = *(const bf16x8*)&Bs[(64 + nhalf * 32 + ni * 16 + lr) * BSTR + ch];
      }
      #pragma unroll
      for (int mi = 0; mi < 4; ++mi)
        #pragma unroll
        for (int ni = 0; ni < 2; ++ni) {
          accg[mi][ni] = __builtin_amdgcn_mfma_f32_16x16x32_bf16(af[mi], bg[ni], accg[mi][ni], 0, 0, 0);
          accu[mi][ni] = __builtin_amdgcn_mfma_f32_16x16x32_bf16(af[mi], bu[ni], accu[mi][ni], 0, 0, 0);
        }
    }
    __syncthreads();
  }

  #pragma unroll
  for (int mi = 0; mi < 4; ++mi)
    #pragma unroll
    for (int r = 0; r < 4; ++r) {
      int row_local = mrow + mi * 16 + q * 4 + r;
      if (row_local >= rows) continue;
      size_t orow = (size_t)(base + row0 + row_local) * I_DIM;
      #pragma unroll
      for (int ni = 0; ni < 2; ++ni) {
        float g = accg[mi][ni][r], u = accu[mi][ni][r];
        float s = g / (1.0f + __expf(-g)) * u;
        hb[orow + c0 + nhalf * 32 + ni * 16 + lr] = f2bf(s);
      }
    }
}

// ---------------- GEMM B: out = h @ Wd, fused Wd transpose-convert ----------------
// block: 128 tokens x 128 cols; waves 2m x 2n; wave = 64m x 64n
__launch_bounds__(256, 3)
__global__ void k_gemm_b(const unsigned short* __restrict__ hb,
                         const float* __restrict__ wdn,
                         float* __restrict__ out,
                         const int* __restrict__ counts) {
  __shared__ unsigned short As[BM * BK];
  __shared__ unsigned short Bs[BM * BSTR];

  int e, row0, base, cnt;
  if (!tile_info(counts, blockIdx.y, e, row0, base, cnt)) return;
  const int rows = (cnt - row0 < BM) ? (cnt - row0) : BM;
  const int n0 = blockIdx.x * 128;

  const int tid = threadIdx.x;
  const int w = tid >> 6, l = tid & 63;
  const int lr = l & 15, q = l >> 4;
  const int asr = l >> 3, akc = (l & 7) * 8;
  const int nloc = ((w & 1) << 6) | l;
  const int kh = (w >> 1) * 32;
  const float* wcol = wdn + (size_t)e * I_DIM * H_DIM + n0 + nloc;
  unsigned int* BsD = (unsigned int*)Bs;
  const int bdst = nloc * (BSTR / 2) + (kh >> 1);

  const int mhalf = w & 1, nhalf = w >> 1;
  const int mrow = mhalf * 64;

  floatx4 acc[4][4];
  #pragma unroll
  for (int i = 0; i < 4; ++i)
    #pragma unroll
    for (int j = 0; j < 4; ++j) acc[i][j] = (floatx4){0,0,0,0};

  const int nk = I_DIM / BK;   // 8
  for (int ki = 0; ki < nk; ++ki) {
    const int kk = ki * BK;
    float bv[32];
    #pragma unroll
    for (int j = 0; j < 32; ++j)
      bv[j] = wcol[(size_t)(kk + kh + j) * H_DIM];
    #pragma unroll
    for (int t = 0; t < 4; ++t) {
      int r = w * 32 + t * 8 + asr;
      int gr = r < rows ? r : rows - 1;
      gld16(&hb[(size_t)(base + row0 + gr) * I_DIM + kk + akc], &As[(w * 32 + t * 8) * BK]);
    }
    #pragma unroll
    for (int jq = 0; jq < 8; ++jq) {
      uint2 d;
      d.x = pk2(bv[4 * jq + 0], bv[4 * jq + 1]);
      d.y = pk2(bv[4 * jq + 2], bv[4 * jq + 3]);
      *(uint2*)&BsD[bdst + jq * 2] = d;
    }
    __syncthreads();
    #pragma unroll
    for (int kf = 0; kf < 2; ++kf) {
      const int ch = (kf * 4 + q) * 8;
      bf16x8 af[4], bf[4];
      #pragma unroll
      for (int mi = 0; mi < 4; ++mi)
        af[mi] = *(const bf16x8*)&As[(mrow + mi * 16 + lr) * BK + ch];
      #pragma unroll
      for (int ni = 0; ni < 4; ++ni)
        bf[ni] = *(const bf16x8*)&Bs[(nhalf * 64 + ni * 16 + lr) * BSTR + ch];
      #pragma unroll
      for (int mi = 0; mi < 4; ++mi)
        #pragma unroll
        for (int ni = 0; ni < 4; ++ni)
          acc[mi][ni] = __builtin_amdgcn_mfma_f32_16x16x32_bf16(af[mi], bf[ni], acc[mi][ni], 0, 0, 0);
    }
    __syncthreads();
  }

  #pragma unroll
  for (int mi = 0; mi < 4; ++mi)
    #pragma unroll
    for (int r = 0; r < 4; ++r) {
      int row_local = mrow + mi * 16 + q * 4 + r;
      if (row_local >= rows) continue;
      size_t orow = (size_t)(base + row0 + row_local) * H_DIM;
      #pragma unroll
      for (int ni = 0; ni < 4; ++ni)
        out[orow + n0 + nhalf * 64 + ni * 16 + lr] = acc[mi][ni][r];
    }
}

// ---------------- launch ----------------
extern "C" void kernel_launch(void* const* d_in, const int* in_sizes, int n_in,
                              void* d_out, int out_size, void* d_ws, size_t ws_size,
                              hipStream_t stream) {
  const float* x      = (const float*)d_in[0];
  const float* wgu    = (const float*)d_in[1];
  const float* wdn    = (const float*)d_in[2];
  const int*   counts = (const int*)d_in[3];
  float* out = (float*)d_out;

  unsigned char* ws = (unsigned char*)d_ws;
  unsigned short* xb = (unsigned short*)(ws);            // 8 MB
  unsigned short* hb = (unsigned short*)(ws + 8388608);  // 4 MB

  k_cvt<<<2048, 256, 0, stream>>>(x, xb);
  // grid.y = 48 covers sum(ceil(c_e/128)) <= 4096/128 + 16 = 48
  k_gemm_a<<<dim3(I_DIM / 64, 48), 256, 0, stream>>>(xb, wgu, hb, counts);
  k_gemm_b<<<dim3(H_DIM / 128, 48), 256, 0, stream>>>(hb, wdn, out, counts);
}